// Round 2
// 973.467 us; speedup vs baseline: 2.2013x; 2.2013x over previous
//
#include <hip/hip_runtime.h>

typedef unsigned short u16;
typedef unsigned int u32;
typedef __attribute__((ext_vector_type(4))) unsigned int u32x4;
typedef __attribute__((ext_vector_type(2))) unsigned int u32x2;
typedef __attribute__((ext_vector_type(8))) short bf16x8;
typedef __attribute__((ext_vector_type(4))) float f32x4;

// d_ws layout (u32 words): six 64x64 weight matrices as bf16 MFMA A-fragments
// (A = W^T; frag order [mt][kt][lane][4 words]); then s_ion (f32).
#define OFF_Wsa1F 0
#define OFF_Wdi1F 2048
#define OFF_Wei1F 4096
#define OFF_WeeiF 6144
#define OFF_We0F  8192
#define OFF_We1F  10240
#define OFF_SION  12288   // float units == u32 units (4B each)

// d_out layout (float elements):
#define OUT_EMB 0
#define OUT_ION 4194304
#define OUT_EE  4194432
#define OUT_EI  37748864

__device__ __forceinline__ float lo2f(u32 v) { return __uint_as_float(v << 16); }
__device__ __forceinline__ float hi2f(u32 v) { return __uint_as_float(v & 0xffff0000u); }
__device__ __forceinline__ u16 f2bf(float f) {
  u32 u = __float_as_uint(f);
  u32 r = (u + 0x7fffu + ((u >> 16) & 1u)) >> 16;
  return (u16)r;
}
__device__ __forceinline__ u32 pack2(float a, float b) {
  return (u32)f2bf(a) | ((u32)f2bf(b) << 16);
}
__device__ __forceinline__ float tfast(float x) {
  x = fminf(fmaxf(x, -15.f), 15.f);
  float e = __expf(2.f * x);
  return (e - 1.f) * __builtin_amdgcn_rcpf(e + 1.f);
}

// Precompute bf16 A-fragments of W^T for v_mfma_f32_16x16x32_bf16.
// A[c][k] = W[k][c]; lane l holds rows c = mt*16+(l&15), k = kt*32+(l>>4)*8 + [0..8).
__global__ void prep_kernel(const float* __restrict__ Wsa1, const float* __restrict__ Wdi1,
                            const float* __restrict__ Wei1, const float* __restrict__ Weei,
                            const float* __restrict__ We0, const float* __restrict__ We1,
                            u32* __restrict__ wsu) {
  const int t = blockIdx.x * blockDim.x + threadIdx.x;
  const int T = gridDim.x * blockDim.x;
  const float* srcs[6] = {Wsa1, Wdi1, Wei1, Weei, We0, We1};
#pragma unroll 1
  for (int idx = t; idx < 6 * 2048; idx += T) {
    const int m = idx >> 11, r = idx & 2047;
    const int wrd = r & 3, lane = (r >> 2) & 63, tk = r >> 8;  // tk = mt*2+kt
    const int mt = tk >> 1, kt = tk & 1;
    const int c = mt * 16 + (lane & 15);
    const int k = kt * 32 + (lane >> 4) * 8 + wrd * 2;
    const float* __restrict__ W = srcs[m];
    wsu[idx] = pack2(W[k * 64 + c], W[(k + 1) * 64 + c]);
  }
}

// s_ion = tanh(feat_ion @ Ws_ei + bs_ei)  [4][64], batch-independent; + feat_ion passthrough
__global__ void sion_kernel(const float* __restrict__ fion, const float* __restrict__ Wsei,
                            const float* __restrict__ bsei, float* __restrict__ ws,
                            float* __restrict__ out) {
  const int t = threadIdx.x;
  if (t < 128) out[OUT_ION + t] = fion[t];
  const int i = t >> 6, c = t & 63;
  float acc = bsei[c];
  for (int k = 0; k < 32; ++k)
    acc += fion[i * 32 + k] * Wsei[k * 64 + c];
  ws[OFF_SION + i * 64 + c] = tfast(acc);
}

struct GP {
  const float *__restrict__ fel; const float *__restrict__ fee; const float *__restrict__ fei;
  const float *__restrict__ dee; const float *__restrict__ dei;
  const float *__restrict__ Wsa0; const float *__restrict__ bsa0; const float *__restrict__ bsa1;
  const float *__restrict__ Wdi0; const float *__restrict__ bdi0; const float *__restrict__ bdi1;
  const float *__restrict__ Wei0; const float *__restrict__ bei0; const float *__restrict__ bei1;
  const float *__restrict__ Wuei; const float *__restrict__ buei; const float *__restrict__ beei;
  const float *__restrict__ Ws0; const float *__restrict__ bs0; const float *__restrict__ Wu0;
  const float *__restrict__ bu0; const float *__restrict__ be0;
  const float *__restrict__ Ws1; const float *__restrict__ bs1; const float *__restrict__ Wu1;
  const float *__restrict__ bu1; const float *__restrict__ be1;
  const float *__restrict__ ws;
  float *__restrict__ out;
};

// In-place per-wave 64ch x 64ch GEMM on 32 edge rows (rows wvu*32..+31) of a
// swizzled bf16 edge tile: E_new[e][c] = tanh(sum_k E[e][k] W[k][c] + b[c]),
// computed transposed: D[c][e] = A(W^T) x B(E^T). Each wave fully owns its rows.
__device__ __forceinline__ void ee_gemm64(u32* s_ee, const u32* __restrict__ Wf,
                                          const float* __restrict__ bias,
                                          int wvu, int ln) {
  const int lhi = ln >> 4, llo = ln & 15;
  u32x4 af[4][2];
#pragma unroll
  for (int mt = 0; mt < 4; ++mt)
#pragma unroll
    for (int kt = 0; kt < 2; ++kt)
      af[mt][kt] = *(const u32x4*)(Wf + ((mt * 2 + kt) * 64 + ln) * 4);
#pragma unroll
  for (int nt = 0; nt < 2; ++nt) {
    const int rowe = wvu * 32 + nt * 16 + llo;
    const int sw = (rowe & 7) << 2;
    u32x4 bf[2];
#pragma unroll
    for (int kt = 0; kt < 2; ++kt)
      bf[kt] = *(const u32x4*)&s_ee[rowe * 32 + ((kt * 16 + lhi * 4) ^ sw)];
    f32x4 acc[4];
#pragma unroll
    for (int mt = 0; mt < 4; ++mt) {
      const float4 bv = *(const float4*)(bias + mt * 16 + lhi * 4);
      acc[mt] = f32x4{bv.x, bv.y, bv.z, bv.w};
    }
#pragma unroll
    for (int kt = 0; kt < 2; ++kt)
#pragma unroll
      for (int mt = 0; mt < 4; ++mt)
        acc[mt] = __builtin_amdgcn_mfma_f32_16x16x32_bf16(
            __builtin_bit_cast(bf16x8, af[mt][kt]),
            __builtin_bit_cast(bf16x8, bf[kt]), acc[mt], 0, 0, 0);
#pragma unroll
    for (int mt = 0; mt < 4; ++mt) {
      u32x2 o;
      o.x = pack2(tfast(acc[mt].x), tfast(acc[mt].y));
      o.y = pack2(tfast(acc[mt].z), tfast(acc[mt].w));
      *(u32x2*)&s_ee[rowe * 32 + ((mt * 8 + lhi * 2) ^ sw)] = o;
    }
  }
}

// Same GEMM on the 64-row el-ion tile. Two waves share each 16-row stripe
// (different output-channel halves), so reads must complete block-wide before
// writes: read fragments -> __syncthreads -> MFMA + write (disjoint words).
__device__ __forceinline__ void ei_gemm64(u32* s_ei, const u32* __restrict__ Wf,
                                          const float* __restrict__ bias,
                                          int wvu, int ln) {
  const int nt = wvu & 3, mh = wvu >> 2;
  const int lhi = ln >> 4, llo = ln & 15;
  const int rowe = nt * 16 + llo;
  const int sw = (rowe & 7) << 2;
  u32x4 bfr[2], af[2][2];
#pragma unroll
  for (int kt = 0; kt < 2; ++kt)
    bfr[kt] = *(const u32x4*)&s_ei[rowe * 32 + ((kt * 16 + lhi * 4) ^ sw)];
#pragma unroll
  for (int m2 = 0; m2 < 2; ++m2)
#pragma unroll
    for (int kt = 0; kt < 2; ++kt)
      af[m2][kt] = *(const u32x4*)(Wf + (((mh * 2 + m2) * 2 + kt) * 64 + ln) * 4);
  __syncthreads();
#pragma unroll
  for (int m2 = 0; m2 < 2; ++m2) {
    const int mt = mh * 2 + m2;
    const float4 bv = *(const float4*)(bias + mt * 16 + lhi * 4);
    f32x4 acc = f32x4{bv.x, bv.y, bv.z, bv.w};
#pragma unroll
    for (int kt = 0; kt < 2; ++kt)
      acc = __builtin_amdgcn_mfma_f32_16x16x32_bf16(
          __builtin_bit_cast(bf16x8, af[m2][kt]),
          __builtin_bit_cast(bf16x8, bfr[kt]), acc, 0, 0, 0);
    u32x2 o;
    o.x = pack2(tfast(acc.x), tfast(acc.y));
    o.y = pack2(tfast(acc.z), tfast(acc.w));
    *(u32x2*)&s_ei[rowe * 32 + ((mt * 8 + lhi * 2) ^ sw)] = o;
  }
}

__global__ __launch_bounds__(512, 4) void gnn_kernel(GP g) {
  const int b = blockIdx.x;
  const int t = threadIdx.x;
  const int ln = t & 63;
  const int wvu = __builtin_amdgcn_readfirstlane(t >> 6);
  const u32* __restrict__ wsu = (const u32*)g.ws;

  // el-el edges: QUADRANT-MAJOR row order (row = q*64 + (i&7)*8 + (j&7),
  // q = (i>=8)*2 + (j>=8)) so layer-2 / edge-update weight choice is wave-uniform.
  // 32 bf16-pair words per row, XOR-swizzled in 4-word chunks for bank-free b128.
  __shared__ __align__(16) u32 s_ee[256 * 32];   // 32768 B
  __shared__ __align__(16) u32 s_ei[64 * 32];    //  8192 B
  __shared__ float s_emb[16 * 128];              //  8192 B
  __shared__ float s_nd[16 * 64];                //  4096 B
  __shared__ float s_agg[16 * 64];               //  4096 B
  __shared__ float s_xel[16 * 32];               //  2048 B
  __shared__ float s_mee[256];                   //  1024 B
  __shared__ float s_mei[64];                    //   256 B

  // ---- P0: masks + feat_el staging (first consumer is after several barriers) ----
  if (t < 256) s_mee[t] = __expf(g.dee[b * 256 + t] * -0.2f);
  if (t < 64)  s_mei[t] = __expf(g.dei[b * 64 + t] * -0.2f);
  s_xel[t] = g.fel[b * 512 + t];

  // ---- P1a: edge-MLP layer 1 (4->64, tanh) -> bf16 rows in LDS ----
  {
    // el-el: wave = (quadrant q, channel-half h); lane = edge-within-quadrant.
    const int q = wvu >> 1, h = wvu & 1;
    const int i_el = ((q >> 1) << 3) + (ln >> 3);
    const int j_el = ((q & 1) << 3) + (ln & 7);
    const int row = q * 64 + ln;                 // permuted row == q*64 + (i&7)*8+(j&7)
    const bool same = (q == 0) || (q == 3);
    const float* __restrict__ W0 = same ? g.Wsa0 : g.Wdi0;
    const float* __restrict__ b0 = same ? g.bsa0 : g.bdi0;
    const float4 xv = *(const float4*)(g.fee + (size_t)(b * 256 + i_el * 16 + j_el) * 4);
    const int sw = (ln & 7) << 2;
#pragma unroll
    for (int u = 0; u < 4; ++u) {
      u32x4 hv;
#pragma unroll
      for (int p2 = 0; p2 < 4; ++p2) {
        const int c = h * 32 + u * 8 + p2 * 2;   // wave-uniform -> scalar weight loads
        const float v0 = tfast(b0[c] + xv.x * W0[c] + xv.y * W0[64 + c] +
                               xv.z * W0[128 + c] + xv.w * W0[192 + c]);
        const float v1 = tfast(b0[c + 1] + xv.x * W0[c + 1] + xv.y * W0[64 + c + 1] +
                               xv.z * W0[128 + c + 1] + xv.w * W0[192 + c + 1]);
        hv[p2] = pack2(v0, v1);
      }
      *(u32x4*)&s_ee[row * 32 + ((h * 16 + u * 4) ^ sw)] = hv;
    }
  }
  {
    // el-ion: lane = edge (64), wave = channel-eighth.
    const int e = ln;
    const float4 xv = *(const float4*)(g.fei + (size_t)(b * 64 + e) * 4);
    u32x4 hv;
#pragma unroll
    for (int p2 = 0; p2 < 4; ++p2) {
      const int c = wvu * 8 + p2 * 2;
      const float v0 = tfast(g.bei0[c] + xv.x * g.Wei0[c] + xv.y * g.Wei0[64 + c] +
                             xv.z * g.Wei0[128 + c] + xv.w * g.Wei0[192 + c]);
      const float v1 = tfast(g.bei0[c + 1] + xv.x * g.Wei0[c + 1] + xv.y * g.Wei0[64 + c + 1] +
                             xv.z * g.Wei0[128 + c + 1] + xv.w * g.Wei0[192 + c + 1]);
      hv[p2] = pack2(v0, v1);
    }
    *(u32x4*)&s_ei[e * 32 + ((wvu * 4) ^ ((e & 7) << 2))] = hv;
  }
  __syncthreads();

  // ---- P1b: edge-MLP layer 2 via MFMA (in-place, per-wave row ownership) ----
  {
    const int q = wvu >> 1;
    const bool same = (q == 0) || (q == 3);
    ee_gemm64(s_ee, wsu + (same ? OFF_Wsa1F : OFF_Wdi1F), same ? g.bsa1 : g.bdi1, wvu, ln);
  }
  ei_gemm64(s_ei, wsu + OFF_Wei1F, g.bei1, wvu, ln);   // contains its own barrier
  __syncthreads();

  // ---- P2a: el-ion aggregation: agg[r][c] = sum_i e[r][i][c]*s_ion[i][c]*mask[r][i] ----
  {
    const int c = t & 63, rr = t >> 6;
    const float* __restrict__ sion = g.ws + OFF_SION;
    const int wIdx = c >> 1;
    const bool hi = c & 1;
#pragma unroll
    for (int rh = 0; rh < 2; ++rh) {
      const int r = rr + rh * 8;
      float a = 0.f;
#pragma unroll
      for (int i = 0; i < 4; ++i) {
        const int row = r * 4 + i;
        const u32 v = s_ei[row * 32 + (wIdx ^ ((row & 7) << 2))];
        a += (hi ? hi2f(v) : lo2f(v)) * sion[i * 64 + c] * s_mei[row];
      }
      s_agg[r * 64 + c] = a;
    }
  }
  __syncthreads();

  // ---- P2b: node update from [feat_el(32), agg(64)] @ Wu_ei(96x128) ----
  {
    const int d = t & 127, gi = t >> 7;
    const float* __restrict__ Wu = g.Wuei;
    float acc[4];
#pragma unroll
    for (int r2 = 0; r2 < 4; ++r2) acc[r2] = g.buei[d];
#pragma unroll 1
    for (int k = 0; k < 32; ++k) {
      const float wk = Wu[k * 128 + d];
#pragma unroll
      for (int r2 = 0; r2 < 4; ++r2) acc[r2] += s_xel[(gi * 4 + r2) * 32 + k] * wk;
    }
#pragma unroll 1
    for (int k = 0; k < 64; ++k) {
      const float wk = Wu[(32 + k) * 128 + d];
#pragma unroll
      for (int r2 = 0; r2 < 4; ++r2) acc[r2] += s_agg[(gi * 4 + r2) * 64 + k] * wk;
    }
#pragma unroll
    for (int r2 = 0; r2 < 4; ++r2) s_emb[(gi * 4 + r2) * 128 + d] = tfast(acc[r2]);
  }

  // ---- P2c: el-ion edge update via MFMA (reads old edges; internal barrier) ----
  ei_gemm64(s_ei, wsu + OFF_WeeiF, g.beei, wvu, ln);
  __syncthreads();

  // ---- P2d: unpack updated el-ion edges to f32 out (coalesced float2) ----
  {
    float2* o = (float2*)(g.out + OUT_EI + (size_t)b * 4096);
#pragma unroll
    for (int ii = 0; ii < 4; ++ii) {
      const int iw = ii * 512 + t;
      const int row = iw >> 5, w = iw & 31;
      const u32 v = s_ei[row * 32 + (w ^ ((row & 7) << 2))];
      o[iw] = make_float2(lo2f(v), hi2f(v));
    }
  }

  // ---- P3/P4: two dense el-el GNN iterations ----
#pragma unroll 1
  for (int it = 0; it < 2; ++it) {
    const float* __restrict__ Ws = it ? g.Ws1 : g.Ws0;
    const float* __restrict__ bs = it ? g.bs1 : g.bs0;
    const float* __restrict__ Wu = it ? g.Wu1 : g.Wu0;
    const float* __restrict__ bu = it ? g.bu1 : g.bu0;
    const float* __restrict__ be = it ? g.be1 : g.be0;
    const u32* __restrict__ WeF = wsu + (it ? OFF_We1F : OFF_We0F);

    // a) sender projection s_nd = tanh(emb @ Ws + bs)
    {
      const int c = t & 63, w8 = t >> 6;
      float a0 = bs[c], a1 = bs[c];
#pragma unroll 1
      for (int k = 0; k < 128; ++k) {
        const float wk = Ws[k * 64 + c];
        a0 += s_emb[w8 * 128 + k] * wk;
        a1 += s_emb[(w8 + 8) * 128 + k] * wk;
      }
      s_nd[w8 * 64 + c] = tfast(a0);
      s_nd[(w8 + 8) * 64 + c] = tfast(a1);
    }
    __syncthreads();

    // b) masked aggregation over senders (permuted edge rows; row&7 == s&7)
    {
      const int c = t & 63, rr = t >> 6;
      const int wIdx = c >> 1;
      const bool hi = c & 1;
#pragma unroll
      for (int rh = 0; rh < 2; ++rh) {
        const int r = rr + rh * 8;
        const int rbase = ((r >> 3) << 7) + ((r & 7) << 3);
        float a = 0.f;
#pragma unroll
        for (int s = 0; s < 16; ++s) {
          const int row = rbase + ((s >> 3) << 6) + (s & 7);
          const u32 v = s_ee[row * 32 + (wIdx ^ ((s & 7) << 2))];
          a += (hi ? hi2f(v) : lo2f(v)) * s_nd[s * 64 + c] * s_mee[r * 16 + s];
        }
        s_agg[r * 64 + c] = a;
      }
    }
    __syncthreads();

    // c) node update from [emb(128), agg(64)] @ Wu(192x128)
    {
      const int d = t & 127, gi = t >> 7;
      float acc[4];
#pragma unroll
      for (int r2 = 0; r2 < 4; ++r2) acc[r2] = bu[d];
#pragma unroll 1
      for (int k = 0; k < 128; ++k) {
        const float wk = Wu[k * 128 + d];
#pragma unroll
        for (int r2 = 0; r2 < 4; ++r2) acc[r2] += s_emb[(gi * 4 + r2) * 128 + k] * wk;
      }
#pragma unroll 1
      for (int k = 0; k < 64; ++k) {
        const float wk = Wu[(128 + k) * 128 + d];
#pragma unroll
        for (int r2 = 0; r2 < 4; ++r2) acc[r2] += s_agg[(gi * 4 + r2) * 64 + k] * wk;
      }
      __syncthreads();   // all reads of old emb complete
#pragma unroll
      for (int r2 = 0; r2 < 4; ++r2) {
        const float v = tfast(acc[r2]);
        s_emb[(gi * 4 + r2) * 128 + d] = v;
        if (it == 1) g.out[OUT_EMB + (size_t)b * 2048 + (gi * 4 + r2) * 128 + d] = v;
      }
    }
    __syncthreads();

    // d) edge update via MFMA, in-place per-wave (b's reads are 2 barriers back)
    ee_gemm64(s_ee, WeF, be, wvu, ln);
    __syncthreads();
  }

  // ---- final: unpack el-el edges to f32 out (permuted rows -> original order) ----
  {
    float2* o = (float2*)(g.out + OUT_EE + (size_t)b * 16384);
#pragma unroll 1
    for (int ii = 0; ii < 16; ++ii) {
      const int iw = ii * 512 + t;               // permuted-space word index
      const int row = iw >> 5, w = iw & 31;
      const u32 v = s_ee[row * 32 + (w ^ ((row & 7) << 2))];
      const int i_el = (((row >> 7) & 1) << 3) | ((row >> 3) & 7);
      const int j_el = (((row >> 6) & 1) << 3) | (row & 7);
      o[(i_el * 16 + j_el) * 32 + w] = make_float2(lo2f(v), hi2f(v));
    }
  }
}

extern "C" void kernel_launch(void* const* d_in, const int* in_sizes, int n_in,
                              void* d_out, int out_size, void* d_ws, size_t ws_size,
                              hipStream_t stream) {
  (void)in_sizes; (void)n_in; (void)out_size; (void)ws_size;
  GP g;
  g.fel  = (const float*)d_in[0];
  g.fee  = (const float*)d_in[1];
  g.fei  = (const float*)d_in[2];
  const float* fion = (const float*)d_in[3];
  g.dee  = (const float*)d_in[5];
  g.dei  = (const float*)d_in[6];

  g.Wei0 = (const float*)d_in[7];  g.bei0 = (const float*)d_in[8];
  const float* Wei1 = (const float*)d_in[9];  g.bei1 = (const float*)d_in[10];
  g.Wsa0 = (const float*)d_in[11]; g.bsa0 = (const float*)d_in[12];
  const float* Wsa1 = (const float*)d_in[13]; g.bsa1 = (const float*)d_in[14];
  g.Wdi0 = (const float*)d_in[15]; g.bdi0 = (const float*)d_in[16];
  const float* Wdi1 = (const float*)d_in[17]; g.bdi1 = (const float*)d_in[18];
  // d_in[19..22] = ion-ion MLP weights: unused (output _edge_ion_ion is dropped)
  const float* Wsei = (const float*)d_in[23];
  const float* bsei = (const float*)d_in[24];
  g.Wuei = (const float*)d_in[25]; g.buei = (const float*)d_in[26];
  const float* Weei = (const float*)d_in[27]; g.beei = (const float*)d_in[28];
  g.Ws0  = (const float*)d_in[29]; g.bs0  = (const float*)d_in[30];
  g.Wu0  = (const float*)d_in[31]; g.bu0  = (const float*)d_in[32];
  const float* We0 = (const float*)d_in[33]; g.be0  = (const float*)d_in[34];
  g.Ws1  = (const float*)d_in[35]; g.bs1  = (const float*)d_in[36];
  g.Wu1  = (const float*)d_in[37]; g.bu1  = (const float*)d_in[38];
  const float* We1 = (const float*)d_in[39]; g.be1  = (const float*)d_in[40];

  float* wsf = (float*)d_ws;
  g.ws = wsf;
  g.out = (float*)d_out;

  hipLaunchKernelGGL(prep_kernel, dim3(16), dim3(256), 0, stream,
                     Wsa1, Wdi1, Wei1, Weei, We0, We1, (u32*)d_ws);
  hipLaunchKernelGGL(sion_kernel, dim3(1), dim3(256), 0, stream,
                     fion, Wsei, bsei, wsf, g.out);
  hipLaunchKernelGGL(gnn_kernel, dim3(2048), dim3(512), 0, stream, g);
}

// Round 8
// 388.268 us; speedup vs baseline: 5.5190x; 2.5072x over previous
//
#include <hip/hip_runtime.h>

typedef unsigned short u16;
typedef unsigned int u32;
typedef __attribute__((ext_vector_type(4))) unsigned int u32x4;
typedef __attribute__((ext_vector_type(2))) unsigned int u32x2;
typedef __attribute__((ext_vector_type(8))) short bf16x8;
typedef __attribute__((ext_vector_type(4))) float f32x4;

// g_frags layout (u32 words): bf16 MFMA A-fragments (A = W^T).
// Edge-path 64x64 (2 kt, single-bf16 K): 2048 words each.
#define OFF_Wsa1F 0
#define OFF_Wdi1F 2048
#define OFF_Wei1F 4096
#define OFF_WeeiF 6144
#define OFF_We0F  8192
#define OFF_We1F  10240
// (12288..15360: legacy L1 pad region — UNUSED since round 7: L1 is f32 VALU)
#define OFF_Wsa0P 12288
#define OFF_Wdi0P 13312
#define OFF_Wei0P 14336
// Node path: SPLIT-K (each orig k duplicated into 2 k-slots, weight repeated;
// B supplies pack2(hi,lo) per channel -> near-f32 activation precision).
// Ws (128x64 -> K_new 256): 4 mt x 8 kt = 8192 words each
#define OFF_Ws0F  15360
#define OFF_Ws1F  23552
// Wuei (96x128 -> K_new 192): 8 mt x 6 kt = 12288 words
#define OFF_WueiF 31744
// Wu (192x128 -> K_new 384): 8 mt x 12 kt = 24576 words each
#define OFF_Wu0F  44032
#define OFF_Wu1F  68608
// s_ion f32 (4x64)
#define OFF_SION  93184
// total 93440 words = 373760 B — static device global (d_ws size unknown)
__device__ u32 g_frags[93440];

// d_out layout (float elements):
#define OUT_EMB 0
#define OUT_ION 4194304
#define OUT_EE  4194432
#define OUT_EI  37748864

__device__ __forceinline__ float lo2f(u32 v) { return __uint_as_float(v << 16); }
__device__ __forceinline__ float hi2f(u32 v) { return __uint_as_float(v & 0xffff0000u); }
__device__ __forceinline__ u16 f2bf(float f) {
  u32 u = __float_as_uint(f);
  u32 r = (u + 0x7fffu + ((u >> 16) & 1u)) >> 16;
  return (u16)r;
}
__device__ __forceinline__ u32 pack2(float a, float b) {
  return (u32)f2bf(a) | ((u32)f2bf(b) << 16);
}
// hi+lo split of one f32 into one u32 (hi in low half = even k-slot)
__device__ __forceinline__ u32 split2(float x) {
  const u32 h = (u32)f2bf(x);
  const float hf = __uint_as_float(h << 16);
  return h | ((u32)f2bf(x - hf) << 16);
}
__device__ __forceinline__ float tfast(float x) {
  x = fminf(fmaxf(x, -15.f), 15.f);
  float e = __expf(2.f * x);
  return (e - 1.f) * __builtin_amdgcn_rcpf(e + 1.f);
}

#define MFMA(a, b, c) __builtin_amdgcn_mfma_f32_16x16x32_bf16( \
    __builtin_bit_cast(bf16x8, a), __builtin_bit_cast(bf16x8, b), c, 0, 0, 0)

// Fragment convention (verified on HW in round 2): A[row][k], lane l holds
// row = mt*16 + (l&15), k = kt*32 + (l>>4)*8 + [0..8) as 4 bf16-pair words
// (word w: even k in low half). C/D: lane l, reg i ->
// D[row = mt*16 + (l>>4)*4 + i][col = l&15].
// Split-K variant: word w of frag (mt,kt) = pack2(W[ko],W[ko]),
// ko = kt*16 + (l>>4)*4 + w.
__global__ void prep_kernel(const float* __restrict__ Wsa1, const float* __restrict__ Wdi1,
                            const float* __restrict__ Wei1, const float* __restrict__ Weei,
                            const float* __restrict__ We0, const float* __restrict__ We1,
                            const float* __restrict__ Wsa0, const float* __restrict__ Wdi0,
                            const float* __restrict__ Wei0,
                            const float* __restrict__ Ws0, const float* __restrict__ Ws1,
                            const float* __restrict__ Wuei,
                            const float* __restrict__ Wu0, const float* __restrict__ Wu1) {
  const int t = blockIdx.x * blockDim.x + threadIdx.x;
  const int T = gridDim.x * blockDim.x;
  const float* s64[6] = {Wsa1, Wdi1, Wei1, Weei, We0, We1};
  const float* sL1[3] = {Wsa0, Wdi0, Wei0};
#pragma unroll 1
  for (int idx = t; idx < 93184; idx += T) {
    u32 val;
    if (idx < 12288) {                       // six 64x64 edge mats, single-bf16 K
      const int m = idx >> 11, r = idx & 2047;
      const int w = r & 3, lane = (r >> 2) & 63, tk = r >> 8;
      const int c = (tk >> 1) * 16 + (lane & 15);
      const int k = (tk & 1) * 32 + (lane >> 4) * 8 + w * 2;
      const float* W = s64[m];
      val = pack2(W[k * 64 + c], W[(k + 1) * 64 + c]);
    } else if (idx < 15360) {                // legacy L1 pads (unused, kept for layout)
      const int i2 = idx - 12288;
      const int m = i2 >> 10, r = i2 & 1023;
      const int w = r & 3, lane = (r >> 2) & 63, mt = r >> 8;
      const int c = mt * 16 + (lane & 15);
      const int k = (lane >> 4) * 8 + w * 2;
      const float* W = sL1[m];
      val = (k < 4) ? pack2(W[k * 64 + c], W[(k + 1) * 64 + c]) : 0u;
    } else if (idx < 31744) {                // Ws0/Ws1 split-K: f = mt*8+kt
      const int i2 = idx - 15360;
      const float* W = (i2 < 8192) ? Ws0 : Ws1;
      const int r = i2 & 8191;
      const int w = r & 3, lane = (r >> 2) & 63, f = r >> 8;   // [0,32)
      const int c = (f >> 3) * 16 + (lane & 15);
      const int ko = (f & 7) * 16 + ((lane >> 4) << 2) + w;    // [0,128)
      const float v = W[ko * 64 + c];
      val = pack2(v, v);
    } else if (idx < 44032) {                // Wuei split-K: f = mt*6+kt
      const int i2 = idx - 31744;
      const int w = i2 & 3, lane = (i2 >> 2) & 63, f = i2 >> 8;  // [0,48)
      const int d = (f / 6) * 16 + (lane & 15);
      const int ko = (f % 6) * 16 + ((lane >> 4) << 2) + w;      // [0,96)
      const float v = Wuei[ko * 128 + d];
      val = pack2(v, v);
    } else {                                 // Wu0/Wu1 split-K: f = mt*12+kt
      const int i2 = idx - 44032;
      const float* W = (i2 < 24576) ? Wu0 : Wu1;
      const int r = (i2 < 24576) ? i2 : i2 - 24576;
      const int w = r & 3, lane = (r >> 2) & 63, f = r >> 8;     // [0,96)
      const int d = (f / 12) * 16 + (lane & 15);
      const int ko = (f % 12) * 16 + ((lane >> 4) << 2) + w;     // [0,192)
      const float v = W[ko * 128 + d];
      val = pack2(v, v);
    }
    g_frags[idx] = val;
  }
}

// s_ion = tanh(feat_ion @ Ws_ei + bs_ei)  [4][64], batch-independent; + feat_ion passthrough
__global__ void sion_kernel(const float* __restrict__ fion, const float* __restrict__ Wsei,
                            const float* __restrict__ bsei, float* __restrict__ out) {
  const int t = threadIdx.x;
  if (t < 128) out[OUT_ION + t] = fion[t];
  const int i = t >> 6, c = t & 63;
  float acc = bsei[c];
  for (int k = 0; k < 32; ++k)
    acc += fion[i * 32 + k] * Wsei[k * 64 + c];
  ((float*)g_frags)[OFF_SION + i * 64 + c] = tfast(acc);
}

struct GP {
  const float *__restrict__ fel; const float *__restrict__ fee; const float *__restrict__ fei;
  const float *__restrict__ dee; const float *__restrict__ dei;
  const float *__restrict__ Wsa0; const float *__restrict__ Wdi0; const float *__restrict__ Wei0;
  const float *__restrict__ bsa0; const float *__restrict__ bsa1;
  const float *__restrict__ bdi0; const float *__restrict__ bdi1;
  const float *__restrict__ bei0; const float *__restrict__ bei1;
  const float *__restrict__ buei; const float *__restrict__ beei;
  const float *__restrict__ bs0; const float *__restrict__ bu0; const float *__restrict__ be0;
  const float *__restrict__ bs1; const float *__restrict__ bu1; const float *__restrict__ be1;
  float *__restrict__ out;
};

// In-place per-wave 64ch x 64ch GEMM on 32 wave-private edge rows (bf16 edges).
__device__ __forceinline__ void ee_gemm64(u32* s_ee, const u32* __restrict__ Wf,
                                          const float* __restrict__ bias,
                                          int wvu, int ln) {
  const int lhi = ln >> 4, llo = ln & 15;
  u32x4 af[4][2];
#pragma unroll
  for (int mt = 0; mt < 4; ++mt)
#pragma unroll
    for (int kt = 0; kt < 2; ++kt)
      af[mt][kt] = *(const u32x4*)(Wf + ((mt * 2 + kt) * 64 + ln) * 4);
#pragma unroll
  for (int nt = 0; nt < 2; ++nt) {
    const int rowe = wvu * 32 + nt * 16 + llo;
    const int sw = (rowe & 7) << 2;
    u32x4 bf[2];
#pragma unroll
    for (int kt = 0; kt < 2; ++kt)
      bf[kt] = *(const u32x4*)&s_ee[rowe * 32 + ((kt * 16 + lhi * 4) ^ sw)];
    f32x4 acc[4];
#pragma unroll
    for (int mt = 0; mt < 4; ++mt) {
      const float4 bv = *(const float4*)(bias + mt * 16 + lhi * 4);
      acc[mt] = f32x4{bv.x, bv.y, bv.z, bv.w};
    }
#pragma unroll
    for (int kt = 0; kt < 2; ++kt)
#pragma unroll
      for (int mt = 0; mt < 4; ++mt)
        acc[mt] = MFMA(af[mt][kt], bf[kt], acc[mt]);
#pragma unroll
    for (int mt = 0; mt < 4; ++mt) {
      u32x2 o;
      o.x = pack2(tfast(acc[mt].x), tfast(acc[mt].y));
      o.y = pack2(tfast(acc[mt].z), tfast(acc[mt].w));
      *(u32x2*)&s_ee[rowe * 32 + ((mt * 8 + lhi * 2) ^ sw)] = o;
    }
  }
}

// 64-row el-ion tile GEMM; two waves share each 16-row stripe (different
// channel halves) -> read frags, block barrier, then MFMA + disjoint writes.
__device__ __forceinline__ void ei_gemm64(u32* s_ei, const u32* __restrict__ Wf,
                                          const float* __restrict__ bias,
                                          int wvu, int ln) {
  const int nt = wvu & 3, mh = wvu >> 2;
  const int lhi = ln >> 4, llo = ln & 15;
  const int rowe = nt * 16 + llo;
  const int sw = (rowe & 7) << 2;
  u32x4 bfr[2], af[2][2];
#pragma unroll
  for (int kt = 0; kt < 2; ++kt)
    bfr[kt] = *(const u32x4*)&s_ei[rowe * 32 + ((kt * 16 + lhi * 4) ^ sw)];
#pragma unroll
  for (int m2 = 0; m2 < 2; ++m2)
#pragma unroll
    for (int kt = 0; kt < 2; ++kt)
      af[m2][kt] = *(const u32x4*)(Wf + (((mh * 2 + m2) * 2 + kt) * 64 + ln) * 4);
  __syncthreads();
#pragma unroll
  for (int m2 = 0; m2 < 2; ++m2) {
    const int mt = mh * 2 + m2;
    const float4 bv = *(const float4*)(bias + mt * 16 + lhi * 4);
    f32x4 acc = f32x4{bv.x, bv.y, bv.z, bv.w};
#pragma unroll
    for (int kt = 0; kt < 2; ++kt)
      acc = MFMA(af[m2][kt], bfr[kt], acc);
    u32x2 o;
    o.x = pack2(tfast(acc.x), tfast(acc.y));
    o.y = pack2(tfast(acc.z), tfast(acc.w));
    *(u32x2*)&s_ei[rowe * 32 + ((mt * 8 + lhi * 2) ^ sw)] = o;
  }
}

__global__ __launch_bounds__(512, 4) void gnn_kernel(GP g) {
  const int b = blockIdx.x;
  const int t = threadIdx.x;
  const int ln = t & 63;
  const int wvu = __builtin_amdgcn_readfirstlane(t >> 6);
  const int lhi = ln >> 4, llo = ln & 15;
  const u32* __restrict__ wsu = g_frags;

  // el-el edges: quadrant-major rows (row = q*64 + (i&7)*8 + (j&7)),
  // 32 bf16-pair words/row, word-XOR swizzle ^((row&7)<<2).
  // Node-path tiles (emb/nd/agg/xel) are SPLIT: word w = pack2(hi,lo) of ch w.
  __shared__ __align__(16) u32 s_ee[256 * 32];   // 32768 B
  __shared__ __align__(16) u32 s_ei[64 * 32];    //  8192 B
  __shared__ __align__(16) u32 s_pool[3072];     // 12288 B (emb + nd)
  __shared__ __align__(16) u32 s_agg[16 * 64];   //  4096 B split agg
  __shared__ __align__(16) u32 s_xel[16 * 32];   //  2048 B split feat_el
  __shared__ float s_mee[256];                   //  1024 B
  __shared__ float s_mei[64];                    //   256 B
  u32* s_emb  = s_pool;                          // [16][128] split emb
  u32* s_nd   = s_pool + 2048;                   // [16][64] split sender proj

  // ---- P0: masks + split feat_el staging ----
  if (t < 256) {
    s_mee[t] = __expf(g.dee[b * 256 + t] * -0.2f);
  } else {
    const int u = t - 256;
    const int r = u >> 4, w = u & 15;
    const float2 f2 = *(const float2*)(g.fel + b * 512 + r * 32 + w * 2);
    u32x2 sx; sx.x = split2(f2.x); sx.y = split2(f2.y);
    *(u32x2*)&s_xel[r * 32 + ((2 * w) ^ ((r & 7) << 2))] = sx;
    if (u < 64) s_mei[u] = __expf(g.dei[b * 64 + u] * -0.2f);
  }
  __syncthreads();

  // ---- P1a: edge MLP layer 1 in f32 VALU (round-2 verified numerics) ----
  {
    // el-el: wave = (quadrant q, channel-half h); lane = edge-within-quadrant.
    const int q = wvu >> 1, h = wvu & 1;
    const int i_el = ((q >> 1) << 3) + (ln >> 3);
    const int j_el = ((q & 1) << 3) + (ln & 7);
    const int row = q * 64 + ln;                 // permuted row
    const bool same = (q == 0) || (q == 3);
    const float* __restrict__ W0 = same ? g.Wsa0 : g.Wdi0;
    const float* __restrict__ b0 = same ? g.bsa0 : g.bdi0;
    const float4 xv = *(const float4*)(g.fee + (size_t)(b * 256 + i_el * 16 + j_el) * 4);
    const int sw = (ln & 7) << 2;
#pragma unroll
    for (int u = 0; u < 4; ++u) {
      u32x4 hv;
#pragma unroll
      for (int p2 = 0; p2 < 4; ++p2) {
        const int c = h * 32 + u * 8 + p2 * 2;   // wave-uniform -> scalar weight loads
        const float v0 = tfast(b0[c] + xv.x * W0[c] + xv.y * W0[64 + c] +
                               xv.z * W0[128 + c] + xv.w * W0[192 + c]);
        const float v1 = tfast(b0[c + 1] + xv.x * W0[c + 1] + xv.y * W0[64 + c + 1] +
                               xv.z * W0[128 + c + 1] + xv.w * W0[192 + c + 1]);
        hv[p2] = pack2(v0, v1);
      }
      *(u32x4*)&s_ee[row * 32 + ((h * 16 + u * 4) ^ sw)] = hv;
    }
  }
  {
    // el-ion: lane = edge (64), wave = channel-eighth.
    const int e = ln;
    const float4 xv = *(const float4*)(g.fei + (size_t)(b * 64 + e) * 4);
    u32x4 hv;
#pragma unroll
    for (int p2 = 0; p2 < 4; ++p2) {
      const int c = wvu * 8 + p2 * 2;
      const float v0 = tfast(g.bei0[c] + xv.x * g.Wei0[c] + xv.y * g.Wei0[64 + c] +
                             xv.z * g.Wei0[128 + c] + xv.w * g.Wei0[192 + c]);
      const float v1 = tfast(g.bei0[c + 1] + xv.x * g.Wei0[c + 1] + xv.y * g.Wei0[64 + c + 1] +
                             xv.z * g.Wei0[128 + c + 1] + xv.w * g.Wei0[192 + c + 1]);
      hv[p2] = pack2(v0, v1);
    }
    *(u32x4*)&s_ei[e * 32 + ((wvu * 4) ^ ((e & 7) << 2))] = hv;
  }
  __syncthreads();

  // ---- P1b: edge MLP layer 2 via MFMA (in place) ----
  {
    const int q = wvu >> 1;
    const bool same = (q == 0) || (q == 3);
    ee_gemm64(s_ee, wsu + (same ? OFF_Wsa1F : OFF_Wdi1F), same ? g.bsa1 : g.bdi1, wvu, ln);
  }
  ei_gemm64(s_ei, wsu + OFF_Wei1F, g.bei1, wvu, ln);   // internal barrier
  __syncthreads();

  // ---- P2a: el-ion aggregation -> split s_agg ----
  {
    const int c2i = t & 31;          // channel-pair index
    const int r = t >> 5;            // receiver 0..15
    const float* __restrict__ sion = (const float*)g_frags + OFF_SION;
    float a0 = 0.f, a1 = 0.f;
#pragma unroll
    for (int i = 0; i < 4; ++i) {
      const int row = r * 4 + i;
      const u32 ev = s_ei[row * 32 + (c2i ^ ((row & 7) << 2))];
      const float2 si = *(const float2*)(sion + i * 64 + c2i * 2);
      const float mk = s_mei[row];
      a0 += lo2f(ev) * si.x * mk;
      a1 += hi2f(ev) * si.y * mk;
    }
    u32x2 o; o.x = split2(a0); o.y = split2(a1);
    *(u32x2*)&s_agg[r * 64 + ((2 * c2i) ^ ((r & 7) << 2))] = o;
  }
  __syncthreads();

  // ---- P2b: node update [xel(32), agg(64)] @ Wuei via MFMA split-K (wave=mt) ----
  {
    const int mt = wvu;
    const int sw = (llo & 7) << 2;
    u32x4 bfr[6];
    bfr[0] = *(const u32x4*)&s_xel[llo * 32 + ((lhi * 4) ^ sw)];
    bfr[1] = *(const u32x4*)&s_xel[llo * 32 + ((16 + lhi * 4) ^ sw)];
#pragma unroll
    for (int k2 = 0; k2 < 4; ++k2)
      bfr[2 + k2] = *(const u32x4*)&s_agg[llo * 64 + ((k2 * 16 + lhi * 4) ^ sw)];
    const float4 bv = *(const float4*)(g.buei + mt * 16 + lhi * 4);
    f32x4 acc = f32x4{bv.x, bv.y, bv.z, bv.w};
#pragma unroll
    for (int kt = 0; kt < 6; ++kt)
      acc = MFMA(*(const u32x4*)(wsu + OFF_WueiF + (mt * 6 + kt) * 256 + ln * 4),
                 bfr[kt], acc);
    u32x4 o;
    o[0] = split2(tfast(acc.x)); o[1] = split2(tfast(acc.y));
    o[2] = split2(tfast(acc.z)); o[3] = split2(tfast(acc.w));
    *(u32x4*)&s_emb[llo * 128 + ((mt * 16 + lhi * 4) ^ sw)] = o;
  }

  // ---- P2c: el-ion edge update via MFMA (internal barrier orders P2b too) ----
  ei_gemm64(s_ei, wsu + OFF_WeeiF, g.beei, wvu, ln);
  __syncthreads();

  // ---- P2d: unpack updated el-ion edges to f32 out ----
  {
    float2* o = (float2*)(g.out + OUT_EI + (size_t)b * 4096);
#pragma unroll
    for (int ii = 0; ii < 4; ++ii) {
      const int iw = ii * 512 + t;
      const int row = iw >> 5, w = iw & 31;
      const u32 v = s_ei[row * 32 + (w ^ ((row & 7) << 2))];
      o[iw] = make_float2(lo2f(v), hi2f(v));
    }
  }

  // ---- P3/P4: two dense el-el GNN iterations ----
#pragma unroll 1
  for (int it = 0; it < 2; ++it) {
    const u32* __restrict__ Wsf = wsu + (it ? OFF_Ws1F : OFF_Ws0F);
    const u32* __restrict__ Wuf = wsu + (it ? OFF_Wu1F : OFF_Wu0F);
    const u32* __restrict__ WeF = wsu + (it ? OFF_We1F : OFF_We0F);
    const float* __restrict__ bs = it ? g.bs1 : g.bs0;
    const float* __restrict__ bu = it ? g.bu1 : g.bu0;
    const float* __restrict__ be = it ? g.be1 : g.be0;

    // (a) sender projection nd = tanh(emb @ Ws + bs): waves 0-3, split-K
    if (wvu < 4) {
      const int mt = wvu;
      const int sw = (llo & 7) << 2;
      const float4 bv = *(const float4*)(bs + mt * 16 + lhi * 4);
      f32x4 acc = f32x4{bv.x, bv.y, bv.z, bv.w};
#pragma unroll
      for (int kt = 0; kt < 8; ++kt) {
        const u32x4 bf = *(const u32x4*)&s_emb[llo * 128 + ((kt * 16 + lhi * 4) ^ sw)];
        const u32x4 af = *(const u32x4*)(Wsf + (mt * 8 + kt) * 256 + ln * 4);
        acc = MFMA(af, bf, acc);
      }
      u32x4 o;
      o[0] = split2(tfast(acc.x)); o[1] = split2(tfast(acc.y));
      o[2] = split2(tfast(acc.z)); o[3] = split2(tfast(acc.w));
      *(u32x4*)&s_nd[llo * 64 + ((mt * 16 + lhi * 4) ^ sw)] = o;
    }
    __syncthreads();

    // (b) masked aggregation over senders (VALU, thread per channel-pair)
    {
      const int c2i = t & 31;
      const int r = t >> 5;
      const int rbase = ((r >> 3) << 7) + ((r & 7) << 3);
      float a0 = 0.f, a1 = 0.f;
#pragma unroll
      for (int s = 0; s < 16; ++s) {
        const int row = rbase + ((s >> 3) << 6) + (s & 7);
        const int swz = (s & 7) << 2;
        const u32 ev = s_ee[row * 32 + (c2i ^ swz)];
        const u32x2 nv = *(const u32x2*)&s_nd[s * 64 + ((2 * c2i) ^ swz)];
        const float mk = s_mee[r * 16 + s];
        a0 += lo2f(ev) * (lo2f(nv.x) + hi2f(nv.x)) * mk;
        a1 += hi2f(ev) * (lo2f(nv.y) + hi2f(nv.y)) * mk;
      }
      u32x2 o; o.x = split2(a0); o.y = split2(a1);
      *(u32x2*)&s_agg[r * 64 + ((2 * c2i) ^ ((r & 7) << 2))] = o;
    }
    __syncthreads();

    // (c) node update [emb(128), agg(64)] @ Wu split-K: read frags, barrier, compute
    u32x4 embf[8], aggf[4];
    {
      const int sw = (llo & 7) << 2;
#pragma unroll
      for (int kt = 0; kt < 8; ++kt)
        embf[kt] = *(const u32x4*)&s_emb[llo * 128 + ((kt * 16 + lhi * 4) ^ sw)];
#pragma unroll
      for (int k2 = 0; k2 < 4; ++k2)
        aggf[k2] = *(const u32x4*)&s_agg[llo * 64 + ((k2 * 16 + lhi * 4) ^ sw)];
    }
    __syncthreads();
    {
      const int mt = wvu;
      const float4 bv = *(const float4*)(bu + mt * 16 + lhi * 4);
      f32x4 acc = f32x4{bv.x, bv.y, bv.z, bv.w};
#pragma unroll
      for (int kt = 0; kt < 8; ++kt)
        acc = MFMA(*(const u32x4*)(Wuf + (mt * 12 + kt) * 256 + ln * 4), embf[kt], acc);
#pragma unroll
      for (int k2 = 0; k2 < 4; ++k2)
        acc = MFMA(*(const u32x4*)(Wuf + (mt * 12 + 8 + k2) * 256 + ln * 4), aggf[k2], acc);
      const float v0 = tfast(acc.x), v1 = tfast(acc.y), v2 = tfast(acc.z), v3 = tfast(acc.w);
      if (it == 1)
        *(float4*)(g.out + OUT_EMB + (size_t)b * 2048 + llo * 128 + mt * 16 + lhi * 4) =
            make_float4(v0, v1, v2, v3);
      u32x4 o;
      o[0] = split2(v0); o[1] = split2(v1); o[2] = split2(v2); o[3] = split2(v3);
      const int sw = (llo & 7) << 2;
      *(u32x4*)&s_emb[llo * 128 + ((mt * 16 + lhi * 4) ^ sw)] = o;
    }

    // (d) edge update via MFMA, wave-private rows (merged into same phase)
    ee_gemm64(s_ee, WeF, be, wvu, ln);
    __syncthreads();
  }

  // ---- final: unpack el-el edges to f32 out (permuted rows -> original) ----
  {
    float2* o = (float2*)(g.out + OUT_EE + (size_t)b * 16384);
#pragma unroll 1
    for (int ii = 0; ii < 16; ++ii) {
      const int iw = ii * 512 + t;
      const int row = iw >> 5, w = iw & 31;
      const u32 v = s_ee[row * 32 + (w ^ ((row & 7) << 2))];
      const int i_el = (((row >> 7) & 1) << 3) | ((row >> 3) & 7);
      const int j_el = (((row >> 6) & 1) << 3) | (row & 7);
      o[(i_el * 16 + j_el) * 32 + w] = make_float2(lo2f(v), hi2f(v));
    }
  }
}

extern "C" void kernel_launch(void* const* d_in, const int* in_sizes, int n_in,
                              void* d_out, int out_size, void* d_ws, size_t ws_size,
                              hipStream_t stream) {
  (void)in_sizes; (void)n_in; (void)out_size; (void)d_ws; (void)ws_size;
  GP g;
  g.fel  = (const float*)d_in[0];
  g.fee  = (const float*)d_in[1];
  g.fei  = (const float*)d_in[2];
  const float* fion = (const float*)d_in[3];
  g.dee  = (const float*)d_in[5];
  g.dei  = (const float*)d_in[6];

  g.Wei0 = (const float*)d_in[7];  g.bei0 = (const float*)d_in[8];
  const float* Wei1 = (const float*)d_in[9];  g.bei1 = (const float*)d_in[10];
  g.Wsa0 = (const float*)d_in[11]; g.bsa0 = (const float*)d_in[12];
  const float* Wsa1 = (const float*)d_in[13]; g.bsa1 = (const float*)d_in[14];
  g.Wdi0 = (const float*)d_in[15]; g.bdi0 = (const float*)d_in[16];
  const float* Wdi1 = (const float*)d_in[17]; g.bdi1 = (const float*)d_in[18];
  // d_in[19..22] = ion-ion MLP weights: unused (output dropped)
  const float* Wsei = (const float*)d_in[23];
  const float* bsei = (const float*)d_in[24];
  const float* Wuei = (const float*)d_in[25]; g.buei = (const float*)d_in[26];
  const float* Weei = (const float*)d_in[27]; g.beei = (const float*)d_in[28];
  const float* Ws0  = (const float*)d_in[29]; g.bs0  = (const float*)d_in[30];
  const float* Wu0  = (const float*)d_in[31]; g.bu0  = (const float*)d_in[32];
  const float* We0  = (const float*)d_in[33]; g.be0  = (const float*)d_in[34];
  const float* Ws1  = (const float*)d_in[35]; g.bs1  = (const float*)d_in[36];
  const float* Wu1  = (const float*)d_in[37]; g.bu1  = (const float*)d_in[38];
  const float* We1  = (const float*)d_in[39]; g.be1  = (const float*)d_in[40];

  g.out = (float*)d_out;

  hipLaunchKernelGGL(prep_kernel, dim3(64), dim3(256), 0, stream,
                     Wsa1, Wdi1, Wei1, Weei, We0, We1,
                     (const float*)d_in[11], (const float*)d_in[15], (const float*)d_in[7],
                     Ws0, Ws1, Wuei, Wu0, Wu1);
  hipLaunchKernelGGL(sion_kernel, dim3(1), dim3(256), 0, stream,
                     fion, Wsei, bsei, g.out);
  hipLaunchKernelGGL(gnn_kernel, dim3(2048), dim3(512), 0, stream, g);
}

// Round 9
// 370.625 us; speedup vs baseline: 5.7817x; 1.0476x over previous
//
#include <hip/hip_runtime.h>

typedef unsigned short u16;
typedef unsigned int u32;
typedef __attribute__((ext_vector_type(4))) unsigned int u32x4;
typedef __attribute__((ext_vector_type(2))) unsigned int u32x2;
typedef __attribute__((ext_vector_type(8))) short bf16x8;
typedef __attribute__((ext_vector_type(4))) float f32x4;

// g_frags layout (u32 words): bf16 MFMA A-fragments (A = W^T).
// Edge-path 64x64 (2 kt, single-bf16 K): 2048 words each.
#define OFF_Wsa1F 0
#define OFF_Wdi1F 2048
#define OFF_Wei1F 4096
#define OFF_WeeiF 6144
#define OFF_We0F  8192
#define OFF_We1F  10240
// Ws (128x64), emb SPLIT-K (hi+lo per channel): 4 mt x 8 kt = 8192 words each
#define OFF_Ws0F  12288
#define OFF_Ws1F  20480
// Wuei (96x128) MIXED: kt0-1 = xel split-K (rows 0-31), kt2-3 = agg single-K
// (rows 32-95): 8 mt x 4 kt = 8192 words
#define OFF_WueiF 28672
// Wu (192x128) MIXED: kt0-7 = emb split-K (rows 0-127), kt8-9 = agg single-K
// (rows 128-191): 8 mt x 10 kt = 20480 words each
#define OFF_Wu0F  36864
#define OFF_Wu1F  57344
// s_ion f32 (4x64)
#define OFF_SION  77824
// total 78080 words = 312320 B — static device global (d_ws size unknown)
__device__ u32 g_frags[78080];

// d_out layout (float elements):
#define OUT_EMB 0
#define OUT_ION 4194304
#define OUT_EE  4194432
#define OUT_EI  37748864

__device__ __forceinline__ float lo2f(u32 v) { return __uint_as_float(v << 16); }
__device__ __forceinline__ float hi2f(u32 v) { return __uint_as_float(v & 0xffff0000u); }
// HW packed f32->bf16 (RNE), 1 instr vs ~10 of manual round-to-nearest-even
__device__ __forceinline__ u32 pack2(float a, float b) {
  u32 r;
  asm("v_cvt_pk_bf16_f32 %0, %1, %2" : "=v"(r) : "v"(a), "v"(b));
  return r;
}
// hi+lo split of one f32 into one u32 (hi in low half = even k-slot)
__device__ __forceinline__ u32 split2(float x) {
  u32 h;
  asm("v_cvt_pk_bf16_f32 %0, %1, 0" : "=v"(h) : "v"(x));
  const float hf = __uint_as_float(h << 16);
  u32 r;
  asm("v_cvt_pk_bf16_f32 %0, %1, %2" : "=v"(r) : "v"(x), "v"(x - hf));
  return r;
}
__device__ __forceinline__ float tfast(float x) {
  x = fminf(fmaxf(x, -15.f), 15.f);
  float e = __expf(2.f * x);
  return (e - 1.f) * __builtin_amdgcn_rcpf(e + 1.f);
}

#define MFMA(a, b, c) __builtin_amdgcn_mfma_f32_16x16x32_bf16( \
    __builtin_bit_cast(bf16x8, a), __builtin_bit_cast(bf16x8, b), c, 0, 0, 0)

// Fragment convention (HW-verified round 2): A[row][k], lane l holds
// row = mt*16 + (l&15), k = kt*32 + (l>>4)*8 + [0..8) as 4 bf16-pair words.
// C/D: lane l, reg i -> D[row = mt*16 + (l>>4)*4 + i][col = l&15].
// Split-K tiles: word w of (mt,kt) = pack2(W[ko],W[ko]), ko = kt*16+(l>>4)*4+w.
__global__ void prep_kernel(const float* __restrict__ Wsa1, const float* __restrict__ Wdi1,
                            const float* __restrict__ Wei1, const float* __restrict__ Weei,
                            const float* __restrict__ We0, const float* __restrict__ We1,
                            const float* __restrict__ Ws0, const float* __restrict__ Ws1,
                            const float* __restrict__ Wuei,
                            const float* __restrict__ Wu0, const float* __restrict__ Wu1) {
  const int t = blockIdx.x * blockDim.x + threadIdx.x;
  const int T = gridDim.x * blockDim.x;
  const float* s64[6] = {Wsa1, Wdi1, Wei1, Weei, We0, We1};
#pragma unroll 1
  for (int idx = t; idx < 77824; idx += T) {
    u32 val;
    if (idx < 12288) {                       // six 64x64 edge mats, single-bf16 K
      const int m = idx >> 11, r = idx & 2047;
      const int w = r & 3, lane = (r >> 2) & 63, tk = r >> 8;
      const int c = (tk >> 1) * 16 + (lane & 15);
      const int k = (tk & 1) * 32 + (lane >> 4) * 8 + w * 2;
      const float* W = s64[m];
      val = pack2(W[k * 64 + c], W[(k + 1) * 64 + c]);
    } else if (idx < 28672) {                // Ws0/Ws1 split-K: f = mt*8+kt
      const int i2 = idx - 12288;
      const float* W = (i2 < 8192) ? Ws0 : Ws1;
      const int r = i2 & 8191;
      const int w = r & 3, lane = (r >> 2) & 63, f = r >> 8;   // [0,32)
      const int c = (f >> 3) * 16 + (lane & 15);
      const int ko = (f & 7) * 16 + ((lane >> 4) << 2) + w;    // [0,128)
      const float v = W[ko * 64 + c];
      val = pack2(v, v);
    } else if (idx < 36864) {                // Wuei mixed: f = mt*4+kt
      const int i2 = idx - 28672;
      const int w = i2 & 3, lane = (i2 >> 2) & 63, f = i2 >> 8;  // [0,32)
      const int mt = f >> 2, kt = f & 3;
      const int d = mt * 16 + (lane & 15);
      if (kt < 2) {                          // xel rows 0-31, split-K
        const int ko = kt * 16 + ((lane >> 4) << 2) + w;
        const float v = Wuei[ko * 128 + d];
        val = pack2(v, v);
      } else {                               // agg rows 32-95, single-K
        const int k = (kt - 2) * 32 + (lane >> 4) * 8 + w * 2;
        val = pack2(Wuei[(32 + k) * 128 + d], Wuei[(33 + k) * 128 + d]);
      }
    } else {                                 // Wu0/Wu1 mixed: f = mt*10+kt
      const int i2 = idx - 36864;
      const float* W = (i2 < 20480) ? Wu0 : Wu1;
      const int r = (i2 < 20480) ? i2 : i2 - 20480;
      const int w = r & 3, lane = (r >> 2) & 63, f = r >> 8;     // [0,80)
      const int mt = f / 10, kt = f % 10;
      const int d = mt * 16 + (lane & 15);
      if (kt < 8) {                          // emb rows 0-127, split-K
        const int ko = kt * 16 + ((lane >> 4) << 2) + w;
        const float v = W[ko * 128 + d];
        val = pack2(v, v);
      } else {                               // agg rows 128-191, single-K
        const int k = (kt - 8) * 32 + (lane >> 4) * 8 + w * 2;
        val = pack2(W[(128 + k) * 128 + d], W[(129 + k) * 128 + d]);
      }
    }
    g_frags[idx] = val;
  }
}

// s_ion = tanh(feat_ion @ Ws_ei + bs_ei)  [4][64], batch-independent; + feat_ion passthrough
__global__ void sion_kernel(const float* __restrict__ fion, const float* __restrict__ Wsei,
                            const float* __restrict__ bsei, float* __restrict__ out) {
  const int t = threadIdx.x;
  if (t < 128) out[OUT_ION + t] = fion[t];
  const int i = t >> 6, c = t & 63;
  float acc = bsei[c];
  for (int k = 0; k < 32; ++k)
    acc += fion[i * 32 + k] * Wsei[k * 64 + c];
  ((float*)g_frags)[OFF_SION + i * 64 + c] = tfast(acc);
}

struct GP {
  const float *__restrict__ fel; const float *__restrict__ fee; const float *__restrict__ fei;
  const float *__restrict__ dee; const float *__restrict__ dei;
  const float *__restrict__ Wsa0; const float *__restrict__ Wdi0; const float *__restrict__ Wei0;
  const float *__restrict__ bsa0; const float *__restrict__ bsa1;
  const float *__restrict__ bdi0; const float *__restrict__ bdi1;
  const float *__restrict__ bei0; const float *__restrict__ bei1;
  const float *__restrict__ buei; const float *__restrict__ beei;
  const float *__restrict__ bs0; const float *__restrict__ bu0; const float *__restrict__ be0;
  const float *__restrict__ bs1; const float *__restrict__ bu1; const float *__restrict__ be1;
  float *__restrict__ out;
};

// In-place per-wave 64ch x 64ch GEMM on 32 wave-private edge rows (bf16 edges).
__device__ __forceinline__ void ee_gemm64(u32* s_ee, const u32* __restrict__ Wf,
                                          const float* __restrict__ bias,
                                          int wvu, int ln) {
  const int lhi = ln >> 4, llo = ln & 15;
  u32x4 af[4][2];
#pragma unroll
  for (int mt = 0; mt < 4; ++mt)
#pragma unroll
    for (int kt = 0; kt < 2; ++kt)
      af[mt][kt] = *(const u32x4*)(Wf + ((mt * 2 + kt) * 64 + ln) * 4);
#pragma unroll
  for (int nt = 0; nt < 2; ++nt) {
    const int rowe = wvu * 32 + nt * 16 + llo;
    const int sw = (rowe & 7) << 2;
    u32x4 bf[2];
#pragma unroll
    for (int kt = 0; kt < 2; ++kt)
      bf[kt] = *(const u32x4*)&s_ee[rowe * 32 + ((kt * 16 + lhi * 4) ^ sw)];
    f32x4 acc[4];
#pragma unroll
    for (int mt = 0; mt < 4; ++mt) {
      const float4 bv = *(const float4*)(bias + mt * 16 + lhi * 4);
      acc[mt] = f32x4{bv.x, bv.y, bv.z, bv.w};
    }
#pragma unroll
    for (int kt = 0; kt < 2; ++kt)
#pragma unroll
      for (int mt = 0; mt < 4; ++mt)
        acc[mt] = MFMA(af[mt][kt], bf[kt], acc[mt]);
#pragma unroll
    for (int mt = 0; mt < 4; ++mt) {
      u32x2 o;
      o.x = pack2(tfast(acc[mt].x), tfast(acc[mt].y));
      o.y = pack2(tfast(acc[mt].z), tfast(acc[mt].w));
      *(u32x2*)&s_ee[rowe * 32 + ((mt * 8 + lhi * 2) ^ sw)] = o;
    }
  }
}

// 64-row el-ion tile GEMM; two waves share each 16-row stripe (different
// channel halves) -> read frags, block barrier, then MFMA + disjoint writes.
__device__ __forceinline__ void ei_gemm64(u32* s_ei, const u32* __restrict__ Wf,
                                          const float* __restrict__ bias,
                                          int wvu, int ln) {
  const int nt = wvu & 3, mh = wvu >> 2;
  const int lhi = ln >> 4, llo = ln & 15;
  const int rowe = nt * 16 + llo;
  const int sw = (rowe & 7) << 2;
  u32x4 bfr[2], af[2][2];
#pragma unroll
  for (int kt = 0; kt < 2; ++kt)
    bfr[kt] = *(const u32x4*)&s_ei[rowe * 32 + ((kt * 16 + lhi * 4) ^ sw)];
#pragma unroll
  for (int m2 = 0; m2 < 2; ++m2)
#pragma unroll
    for (int kt = 0; kt < 2; ++kt)
      af[m2][kt] = *(const u32x4*)(Wf + (((mh * 2 + m2) * 2 + kt) * 64 + ln) * 4);
  __syncthreads();
#pragma unroll
  for (int m2 = 0; m2 < 2; ++m2) {
    const int mt = mh * 2 + m2;
    const float4 bv = *(const float4*)(bias + mt * 16 + lhi * 4);
    f32x4 acc = f32x4{bv.x, bv.y, bv.z, bv.w};
#pragma unroll
    for (int kt = 0; kt < 2; ++kt)
      acc = MFMA(af[m2][kt], bfr[kt], acc);
    u32x2 o;
    o.x = pack2(tfast(acc.x), tfast(acc.y));
    o.y = pack2(tfast(acc.z), tfast(acc.w));
    *(u32x2*)&s_ei[rowe * 32 + ((mt * 8 + lhi * 2) ^ sw)] = o;
  }
}

__global__ __launch_bounds__(512, 4) void gnn_kernel(GP g) {
  const int b = blockIdx.x;
  const int t = threadIdx.x;
  const int ln = t & 63;
  const int wvu = __builtin_amdgcn_readfirstlane(t >> 6);
  const int lhi = ln >> 4, llo = ln & 15;
  const u32* __restrict__ wsu = g_frags;

  // el-el edges: quadrant-major rows (row = q*64 + (i&7)*8 + (j&7)),
  // 32 bf16-pair words/row, word-XOR swizzle ^((row&7)<<2).
  // emb SPLIT (word = pack2(hi,lo)); nd/agg plain bf16 (word = 2 channels).
  // LDS total 53248 B -> 3 blocks/CU.
  __shared__ __align__(16) u32 s_ee[256 * 32];   // 32768 B
  __shared__ __align__(16) u32 s_ei[64 * 32];    //  8192 B
  __shared__ __align__(16) u32 s_pool[2560];     // 10240 B: emb split + nd/xel
  __shared__ __align__(16) u32 s_agg[16 * 32];   //  2048 B bf16 agg
  u32* s_emb = s_pool;                           // [16][128] split emb
  u32* s_nx  = s_pool + 2048;                    // [16][32]: xel split, then nd bf16

  // ---- P0: per-thread mask registers + split feat_el staging ----
  float mee[16];                                 // mask row r = t>>5 (matches P3b)
  {
    const float4* dr = (const float4*)(g.dee + b * 256 + (t >> 5) * 16);
#pragma unroll
    for (int j4 = 0; j4 < 4; ++j4) {
      const float4 d4 = dr[j4];
      mee[j4 * 4 + 0] = __expf(d4.x * -0.2f);
      mee[j4 * 4 + 1] = __expf(d4.y * -0.2f);
      mee[j4 * 4 + 2] = __expf(d4.z * -0.2f);
      mee[j4 * 4 + 3] = __expf(d4.w * -0.2f);
    }
  }
  if (t < 256) {
    const int r = t >> 4, w = t & 15;
    const float2 f2 = *(const float2*)(g.fel + b * 512 + r * 32 + w * 2);
    u32x2 sx; sx.x = split2(f2.x); sx.y = split2(f2.y);
    *(u32x2*)&s_nx[r * 32 + ((2 * w) ^ ((r & 7) << 2))] = sx;
  }
  __syncthreads();

  // ---- P1a: edge MLP layer 1 in f32 VALU (verified numerics) ----
  {
    const int q = wvu >> 1, h = wvu & 1;
    const int i_el = ((q >> 1) << 3) + (ln >> 3);
    const int j_el = ((q & 1) << 3) + (ln & 7);
    const int row = q * 64 + ln;                 // permuted row
    const bool same = (q == 0) || (q == 3);
    const float* __restrict__ W0 = same ? g.Wsa0 : g.Wdi0;
    const float* __restrict__ b0 = same ? g.bsa0 : g.bdi0;
    const float4 xv = *(const float4*)(g.fee + (size_t)(b * 256 + i_el * 16 + j_el) * 4);
    const int sw = (ln & 7) << 2;
#pragma unroll
    for (int u = 0; u < 4; ++u) {
      u32x4 hv;
#pragma unroll
      for (int p2 = 0; p2 < 4; ++p2) {
        const int c = h * 32 + u * 8 + p2 * 2;   // wave-uniform -> scalar weight loads
        const float v0 = tfast(b0[c] + xv.x * W0[c] + xv.y * W0[64 + c] +
                               xv.z * W0[128 + c] + xv.w * W0[192 + c]);
        const float v1 = tfast(b0[c + 1] + xv.x * W0[c + 1] + xv.y * W0[64 + c + 1] +
                               xv.z * W0[128 + c + 1] + xv.w * W0[192 + c + 1]);
        hv[p2] = pack2(v0, v1);
      }
      *(u32x4*)&s_ee[row * 32 + ((h * 16 + u * 4) ^ sw)] = hv;
    }
  }
  {
    const int e = ln;
    const float4 xv = *(const float4*)(g.fei + (size_t)(b * 64 + e) * 4);
    u32x4 hv;
#pragma unroll
    for (int p2 = 0; p2 < 4; ++p2) {
      const int c = wvu * 8 + p2 * 2;
      const float v0 = tfast(g.bei0[c] + xv.x * g.Wei0[c] + xv.y * g.Wei0[64 + c] +
                             xv.z * g.Wei0[128 + c] + xv.w * g.Wei0[192 + c]);
      const float v1 = tfast(g.bei0[c + 1] + xv.x * g.Wei0[c + 1] + xv.y * g.Wei0[64 + c + 1] +
                             xv.z * g.Wei0[128 + c + 1] + xv.w * g.Wei0[192 + c + 1]);
      hv[p2] = pack2(v0, v1);
    }
    *(u32x4*)&s_ei[e * 32 + ((wvu * 4) ^ ((e & 7) << 2))] = hv;
  }
  __syncthreads();

  // ---- P1b: edge MLP layer 2 via MFMA (in place) ----
  {
    const int q = wvu >> 1;
    const bool same = (q == 0) || (q == 3);
    ee_gemm64(s_ee, wsu + (same ? OFF_Wsa1F : OFF_Wdi1F), same ? g.bsa1 : g.bdi1, wvu, ln);
  }
  ei_gemm64(s_ei, wsu + OFF_Wei1F, g.bei1, wvu, ln);   // internal barrier
  __syncthreads();

  // ---- P2a: el-ion aggregation -> bf16 s_agg (mei inline from global) ----
  {
    const int c2i = t & 31, r = t >> 5;
    const float* __restrict__ sion = (const float*)g_frags + OFF_SION;
    const float4 di4 = *(const float4*)(g.dei + b * 64 + r * 4);
    const float mk[4] = {__expf(di4.x * -0.2f), __expf(di4.y * -0.2f),
                         __expf(di4.z * -0.2f), __expf(di4.w * -0.2f)};
    float a0 = 0.f, a1 = 0.f;
#pragma unroll
    for (int i = 0; i < 4; ++i) {
      const int row = r * 4 + i;
      const u32 ev = s_ei[row * 32 + (c2i ^ ((row & 7) << 2))];
      const float2 si = *(const float2*)(sion + i * 64 + c2i * 2);
      a0 += lo2f(ev) * si.x * mk[i];
      a1 += hi2f(ev) * si.y * mk[i];
    }
    s_agg[r * 32 + (c2i ^ ((r & 7) << 2))] = pack2(a0, a1);
  }
  __syncthreads();

  // ---- P2b: node update [xel(32,split), agg(64,bf16)] @ Wuei via MFMA ----
  {
    const int mt = wvu;
    const int sw = (llo & 7) << 2;
    u32x4 bfr[4];
    bfr[0] = *(const u32x4*)&s_nx[llo * 32 + ((lhi * 4) ^ sw)];
    bfr[1] = *(const u32x4*)&s_nx[llo * 32 + ((16 + lhi * 4) ^ sw)];
    bfr[2] = *(const u32x4*)&s_agg[llo * 32 + ((lhi * 4) ^ sw)];
    bfr[3] = *(const u32x4*)&s_agg[llo * 32 + ((16 + lhi * 4) ^ sw)];
    const float4 bv = *(const float4*)(g.buei + mt * 16 + lhi * 4);
    f32x4 acc = f32x4{bv.x, bv.y, bv.z, bv.w};
#pragma unroll
    for (int kt = 0; kt < 4; ++kt)
      acc = MFMA(*(const u32x4*)(wsu + OFF_WueiF + (mt * 4 + kt) * 256 + ln * 4),
                 bfr[kt], acc);
    u32x4 o;
    o[0] = split2(tfast(acc.x)); o[1] = split2(tfast(acc.y));
    o[2] = split2(tfast(acc.z)); o[3] = split2(tfast(acc.w));
    *(u32x4*)&s_emb[llo * 128 + ((mt * 16 + lhi * 4) ^ sw)] = o;
  }

  // ---- P2c: el-ion edge update via MFMA (internal barrier orders P2b too) ----
  ei_gemm64(s_ei, wsu + OFF_WeeiF, g.beei, wvu, ln);
  __syncthreads();

  // ---- P2d: unpack updated el-ion edges to f32 out (float4 stores) ----
  {
    float4* o4 = (float4*)(g.out + OUT_EI + (size_t)b * 4096);
#pragma unroll
    for (int ii = 0; ii < 2; ++ii) {
      const int iw2 = ii * 1024 + t * 2;           // even word index
      const int row = iw2 >> 5, w = iw2 & 31;
      const u32x2 v = *(const u32x2*)&s_ei[row * 32 + (w ^ ((row & 7) << 2))];
      o4[iw2 >> 1] = make_float4(lo2f(v.x), hi2f(v.x), lo2f(v.y), hi2f(v.y));
    }
  }

  // ---- P3/P4: two dense el-el GNN iterations ----
#pragma unroll 1
  for (int it = 0; it < 2; ++it) {
    const u32* __restrict__ Wsf = wsu + (it ? OFF_Ws1F : OFF_Ws0F);
    const u32* __restrict__ Wuf = wsu + (it ? OFF_Wu1F : OFF_Wu0F);
    const u32* __restrict__ WeF = wsu + (it ? OFF_We1F : OFF_We0F);
    const float* __restrict__ bs = it ? g.bs1 : g.bs0;
    const float* __restrict__ bu = it ? g.bu1 : g.bu0;
    const float* __restrict__ be = it ? g.be1 : g.be0;

    // (a) sender projection nd = tanh(emb @ Ws + bs): waves 0-3, split-K emb
    if (wvu < 4) {
      const int mt = wvu;
      const int sw = (llo & 7) << 2;
      const float4 bv = *(const float4*)(bs + mt * 16 + lhi * 4);
      f32x4 acc = f32x4{bv.x, bv.y, bv.z, bv.w};
#pragma unroll
      for (int kt = 0; kt < 8; ++kt) {
        const u32x4 bf = *(const u32x4*)&s_emb[llo * 128 + ((kt * 16 + lhi * 4) ^ sw)];
        acc = MFMA(*(const u32x4*)(Wsf + (mt * 8 + kt) * 256 + ln * 4), bf, acc);
      }
      u32x2 o;
      o.x = pack2(tfast(acc.x), tfast(acc.y));
      o.y = pack2(tfast(acc.z), tfast(acc.w));
      *(u32x2*)&s_nx[llo * 32 + ((mt * 8 + lhi * 2) ^ sw)] = o;   // nd (xel dead)
    }
    __syncthreads();

    // (b) masked aggregation over senders (VALU; mask from registers)
    {
      const int c2i = t & 31, r = t >> 5;
      const int rbase = ((r >> 3) << 7) + ((r & 7) << 3);
      float a0 = 0.f, a1 = 0.f;
#pragma unroll
      for (int s = 0; s < 16; ++s) {
        const int row = rbase + ((s >> 3) << 6) + (s & 7);
        const int swz = (s & 7) << 2;
        const u32 ev = s_ee[row * 32 + (c2i ^ swz)];
        const u32 nv = s_nx[s * 32 + (c2i ^ swz)];
        a0 += lo2f(ev) * lo2f(nv) * mee[s];
        a1 += hi2f(ev) * hi2f(nv) * mee[s];
      }
      s_agg[r * 32 + (c2i ^ ((r & 7) << 2))] = pack2(a0, a1);
    }
    __syncthreads();

    // (c) node update [emb(128,split), agg(64,bf16)] @ Wu: read, barrier, compute
    u32x4 embf[8], aggf[2];
    {
      const int sw = (llo & 7) << 2;
#pragma unroll
      for (int kt = 0; kt < 8; ++kt)
        embf[kt] = *(const u32x4*)&s_emb[llo * 128 + ((kt * 16 + lhi * 4) ^ sw)];
      aggf[0] = *(const u32x4*)&s_agg[llo * 32 + ((lhi * 4) ^ sw)];
      aggf[1] = *(const u32x4*)&s_agg[llo * 32 + ((16 + lhi * 4) ^ sw)];
    }
    __syncthreads();
    {
      const int mt = wvu;
      const float4 bv = *(const float4*)(bu + mt * 16 + lhi * 4);
      f32x4 acc = f32x4{bv.x, bv.y, bv.z, bv.w};
#pragma unroll
      for (int kt = 0; kt < 8; ++kt)
        acc = MFMA(*(const u32x4*)(Wuf + (mt * 10 + kt) * 256 + ln * 4), embf[kt], acc);
#pragma unroll
      for (int k2 = 0; k2 < 2; ++k2)
        acc = MFMA(*(const u32x4*)(Wuf + (mt * 10 + 8 + k2) * 256 + ln * 4), aggf[k2], acc);
      const float v0 = tfast(acc.x), v1 = tfast(acc.y), v2 = tfast(acc.z), v3 = tfast(acc.w);
      if (it == 1)
        *(float4*)(g.out + OUT_EMB + (size_t)b * 2048 + llo * 128 + mt * 16 + lhi * 4) =
            make_float4(v0, v1, v2, v3);
      u32x4 o;
      o[0] = split2(v0); o[1] = split2(v1); o[2] = split2(v2); o[3] = split2(v3);
      const int sw = (llo & 7) << 2;
      *(u32x4*)&s_emb[llo * 128 + ((mt * 16 + lhi * 4) ^ sw)] = o;
    }

    // (d) edge update via MFMA, wave-private rows
    ee_gemm64(s_ee, WeF, be, wvu, ln);
    __syncthreads();
  }

  // ---- final: unpack el-el edges to f32 out (permuted rows -> original) ----
  {
    float4* o4 = (float4*)(g.out + OUT_EE + (size_t)b * 16384);
#pragma unroll 1
    for (int ii = 0; ii < 8; ++ii) {
      const int iw2 = ii * 1024 + t * 2;           // even word index
      const int row = iw2 >> 5, w = iw2 & 31;
      const u32x2 v = *(const u32x2*)&s_ee[row * 32 + (w ^ ((row & 7) << 2))];
      const int i_el = (((row >> 7) & 1) << 3) | ((row >> 3) & 7);
      const int j_el = (((row >> 6) & 1) << 3) | (row & 7);
      o4[(i_el * 16 + j_el) * 16 + (w >> 1)] =
          make_float4(lo2f(v.x), hi2f(v.x), lo2f(v.y), hi2f(v.y));
    }
  }
}

extern "C" void kernel_launch(void* const* d_in, const int* in_sizes, int n_in,
                              void* d_out, int out_size, void* d_ws, size_t ws_size,
                              hipStream_t stream) {
  (void)in_sizes; (void)n_in; (void)out_size; (void)d_ws; (void)ws_size;
  GP g;
  g.fel  = (const float*)d_in[0];
  g.fee  = (const float*)d_in[1];
  g.fei  = (const float*)d_in[2];
  const float* fion = (const float*)d_in[3];
  g.dee  = (const float*)d_in[5];
  g.dei  = (const float*)d_in[6];

  g.Wei0 = (const float*)d_in[7];  g.bei0 = (const float*)d_in[8];
  const float* Wei1 = (const float*)d_in[9];  g.bei1 = (const float*)d_in[10];
  g.Wsa0 = (const float*)d_in[11]; g.bsa0 = (const float*)d_in[12];
  const float* Wsa1 = (const float*)d_in[13]; g.bsa1 = (const float*)d_in[14];
  g.Wdi0 = (const float*)d_in[15]; g.bdi0 = (const float*)d_in[16];
  const float* Wdi1 = (const float*)d_in[17]; g.bdi1 = (const float*)d_in[18];
  // d_in[19..22] = ion-ion MLP weights: unused (output dropped)
  const float* Wsei = (const float*)d_in[23];
  const float* bsei = (const float*)d_in[24];
  const float* Wuei = (const float*)d_in[25]; g.buei = (const float*)d_in[26];
  const float* Weei = (const float*)d_in[27]; g.beei = (const float*)d_in[28];
  const float* Ws0  = (const float*)d_in[29]; g.bs0  = (const float*)d_in[30];
  const float* Wu0  = (const float*)d_in[31]; g.bu0  = (const float*)d_in[32];
  const float* We0  = (const float*)d_in[33]; g.be0  = (const float*)d_in[34];
  const float* Ws1  = (const float*)d_in[35]; g.bs1  = (const float*)d_in[36];
  const float* Wu1  = (const float*)d_in[37]; g.bu1  = (const float*)d_in[38];
  const float* We1  = (const float*)d_in[39]; g.be1  = (const float*)d_in[40];

  g.out = (float*)d_out;

  hipLaunchKernelGGL(prep_kernel, dim3(64), dim3(256), 0, stream,
                     Wsa1, Wdi1, Wei1, Weei, We0, We1,
                     Ws0, Ws1, Wuei, Wu0, Wu1);
  hipLaunchKernelGGL(sion_kernel, dim3(1), dim3(256), 0, stream,
                     fion, Wsei, bsei, g.out);
  hipLaunchKernelGGL(gnn_kernel, dim3(2048), dim3(512), 0, stream, g);
}